// Round 1
// baseline (8232.875 us; speedup 1.0000x reference)
//
#include <hip/hip_runtime.h>
#include <math.h>

// ---------------------------------------------------------------------------
// Multi_Adaptation_Module: content SA + style SA (channel attn) + cross attn.
// B=4, C=512, H=W=64 (N=4096). All fp32 (output magnitudes reach ~500 and the
// absmax threshold is 0.11, so low-precision matmul is deferred to later
// rounds with bf16-split techniques).
//
// One parametric fp32 GEMM (128x128 tile, BK=8, 8x8 micro-tile) serves:
//   conv1x1:       out[o,i] = sum_c W[o,c] * in[c,i]          (A=[M,K], B=[K,N])
//   energy (QK^T): E[i,j]   = sum_c q[c,i] * k[c,j]           (A=[K,M] "trans")
//   PV:            o[c,i]   = sum_j v[c,j] * attn[i,j]        (B=[N,K] "trans")
//   style energy:  E[c,d]   = sum_i f[c,i] * g[d,i]           (B trans)
//   style out:     o[c,i]   = sum_d attn[d,c] * h[d,i]        (A trans)
// MVN (mean/unbiased-var per (b,c)) is fused into the B-operand load.
// N x N attention is processed in query slabs (energy slab materialized in ws).
// ---------------------------------------------------------------------------

#define BMT 128
#define BNT 128
#define BKT 8

__device__ __forceinline__ float wave_red_sum(float v) {
#pragma unroll
  for (int off = 32; off > 0; off >>= 1) v += __shfl_xor(v, off, 64);
  return v;
}
__device__ __forceinline__ float wave_red_max(float v) {
#pragma unroll
  for (int off = 32; off > 0; off >>= 1) v = fmaxf(v, __shfl_xor(v, off, 64));
  return v;
}

// per-row mean + rstd (unbiased var, eps=1e-5). L multiple of 1024.
__global__ __launch_bounds__(256) void row_stats_k(const float* __restrict__ x,
                                                   float* __restrict__ mean,
                                                   float* __restrict__ rstd,
                                                   int L) {
  long row = blockIdx.x;
  const float* p = x + row * (long)L;
  int t = threadIdx.x;
  float s = 0.f, ss = 0.f;
  for (int i = t * 4; i < L; i += 1024) {
    float4 v = *(const float4*)(p + i);
    s += v.x + v.y + v.z + v.w;
    ss += v.x * v.x + v.y * v.y + v.z * v.z + v.w * v.w;
  }
  __shared__ float rs_[4], rss_[4];
  int wid = t >> 6, lane = t & 63;
  s = wave_red_sum(s);
  ss = wave_red_sum(ss);
  if (lane == 0) { rs_[wid] = s; rss_[wid] = ss; }
  __syncthreads();
  if (t == 0) {
    float S = rs_[0] + rs_[1] + rs_[2] + rs_[3];
    float SS = rss_[0] + rss_[1] + rss_[2] + rss_[3];
    float m = S / (float)L;
    float var = (SS - (float)L * m * m) / (float)(L - 1);
    mean[row] = m;
    rstd[row] = rsqrtf(var + 1e-5f);
  }
}

// in-place row softmax; L in {512, 4096} (multiple of 256, <= 4096)
__global__ __launch_bounds__(256) void softmax_rows_k(float* __restrict__ E, int L) {
  long row = blockIdx.x;
  float* p = E + row * (long)L;
  int t = threadIdx.x;
  int nv = L >> 8;  // elems per thread (max 16)
  float v[16];
  float mx = -3.4e38f;
  for (int i = 0; i < nv; ++i) {
    v[i] = p[t + (i << 8)];
    mx = fmaxf(mx, v[i]);
  }
  __shared__ float red[4];
  int wid = t >> 6, lane = t & 63;
  mx = wave_red_max(mx);
  if (lane == 0) red[wid] = mx;
  __syncthreads();
  mx = fmaxf(fmaxf(red[0], red[1]), fmaxf(red[2], red[3]));
  float s = 0.f;
  for (int i = 0; i < nv; ++i) {
    v[i] = __expf(v[i] - mx);
    s += v[i];
  }
  __syncthreads();
  s = wave_red_sum(s);
  if (lane == 0) red[wid] = s;
  __syncthreads();
  s = red[0] + red[1] + red[2] + red[3];
  float inv = 1.f / s;
  for (int i = 0; i < nv; ++i) p[t + (i << 8)] = v[i] * inv;
}

// Parametric fp32 GEMM. out[b][m][n] = sum_k A[m,k]*B[k,n] (+bias[m]) (+res).
// ATR: A stored [K,M] row-major (lda = row stride). else [M,K].
// BTR: B stored [N,K] row-major. else [K,N].
// NORMB (only with !BTR): B[k][n] -> (B[k][n]-mean[b*sBS+k])*rstd[b*sBS+k]
template <bool ATR, bool BTR, bool NORMB, bool HASBIAS, bool HASRES>
__global__ __launch_bounds__(256) void gemm_k(
    const float* __restrict__ A, long aBS, int lda,
    const float* __restrict__ Bm, long bBS, int ldb,
    float* __restrict__ O, long oBS, int ldo,
    const float* __restrict__ bias,
    const float* __restrict__ res, long rBS,
    const float* __restrict__ mean, const float* __restrict__ rstd, int sBS,
    int M, int N, int K) {
  __shared__ float As[BKT][BMT];
  __shared__ float Bs[BKT][BNT];
  const int b = blockIdx.z;
  const float* Ab = A + (long)b * aBS;
  const float* Bb = Bm + (long)b * bBS;
  const int m0 = blockIdx.y * BMT, n0 = blockIdx.x * BNT;
  const int t = threadIdx.x;
  const int tx = t & 15, ty = t >> 4;
  float acc[8][8];
#pragma unroll
  for (int i = 0; i < 8; ++i)
#pragma unroll
    for (int j = 0; j < 8; ++j) acc[i][j] = 0.f;

  for (int k0 = 0; k0 < K; k0 += BKT) {
    if (ATR) {
      int k = t >> 5, m = (t & 31) << 2;
      float4 v = *(const float4*)(Ab + (long)(k0 + k) * lda + (m0 + m));
      *(float4*)(&As[k][m]) = v;
    } else {
      int m = t >> 1, k = (t & 1) << 2;
      float4 v = *(const float4*)(Ab + (long)(m0 + m) * lda + (k0 + k));
      As[k + 0][m] = v.x;
      As[k + 1][m] = v.y;
      As[k + 2][m] = v.z;
      As[k + 3][m] = v.w;
    }
    if (BTR) {
      int n = t >> 1, k = (t & 1) << 2;
      float4 v = *(const float4*)(Bb + (long)(n0 + n) * ldb + (k0 + k));
      Bs[k + 0][n] = v.x;
      Bs[k + 1][n] = v.y;
      Bs[k + 2][n] = v.z;
      Bs[k + 3][n] = v.w;
    } else {
      int k = t >> 5, n = (t & 31) << 2;
      float4 v = *(const float4*)(Bb + (long)(k0 + k) * ldb + (n0 + n));
      if (NORMB) {
        float mv = mean[(long)b * sBS + k0 + k];
        float rv = rstd[(long)b * sBS + k0 + k];
        v.x = (v.x - mv) * rv;
        v.y = (v.y - mv) * rv;
        v.z = (v.z - mv) * rv;
        v.w = (v.w - mv) * rv;
      }
      *(float4*)(&Bs[k][n]) = v;
    }
    __syncthreads();
#pragma unroll
    for (int k = 0; k < BKT; ++k) {
      float ar[8], br[8];
      *(float4*)(ar) = *(const float4*)(&As[k][ty << 2]);
      *(float4*)(ar + 4) = *(const float4*)(&As[k][(ty << 2) + 64]);
      *(float4*)(br) = *(const float4*)(&Bs[k][tx << 2]);
      *(float4*)(br + 4) = *(const float4*)(&Bs[k][(tx << 2) + 64]);
#pragma unroll
      for (int i = 0; i < 8; ++i)
#pragma unroll
        for (int j = 0; j < 8; ++j) acc[i][j] = fmaf(ar[i], br[j], acc[i][j]);
    }
    __syncthreads();
  }

  float* Ob = O + (long)b * oBS;
  const float* Rb = HASRES ? (res + (long)b * rBS) : nullptr;
#pragma unroll
  for (int i = 0; i < 8; ++i) {
    int m = m0 + ((i & 4) << 4) + (ty << 2) + (i & 3);
    float bb = HASBIAS ? bias[m] : 0.f;
#pragma unroll
    for (int jh = 0; jh < 2; ++jh) {
      int n = n0 + jh * 64 + (tx << 2);
      float4 v;
      v.x = acc[i][jh * 4 + 0] + bb;
      v.y = acc[i][jh * 4 + 1] + bb;
      v.z = acc[i][jh * 4 + 2] + bb;
      v.w = acc[i][jh * 4 + 3] + bb;
      if (HASRES) {
        float4 rv = *(const float4*)(Rb + (long)m * ldo + n);
        v.x += rv.x;
        v.y += rv.y;
        v.z += rv.z;
        v.w += rv.w;
      }
      *(float4*)(Ob + (long)m * ldo + n) = v;
    }
  }
}

extern "C" void kernel_launch(void* const* d_in, const int* in_sizes, int n_in,
                              void* d_out, int out_size, void* d_ws,
                              size_t ws_size, hipStream_t stream) {
  (void)in_sizes;
  (void)n_in;
  (void)out_size;
  const int B = 4, C = 512, Nsp = 4096;
  const long CN = (long)C * Nsp;  // 2,097,152 floats per batch image
  const long CC = (long)C * C;    // 262,144

  const float* xc = (const float*)d_in[0];  // content_feat
  const float* xs = (const float*)d_in[1];  // style_feat
  const float* cw = (const float*)d_in[2];  // csa_w [4,C,C]
  const float* cb = (const float*)d_in[3];  // csa_b [4,C]
  const float* sw = (const float*)d_in[4];  // ssa_w
  const float* sb = (const float*)d_in[5];  // ssa_b
  const float* aw = (const float*)d_in[6];  // ca_w
  const float* abias = (const float*)d_in[7];  // ca_b
  float* out = (float*)d_out;
  float* ws = (float*)d_ws;

  // ws layout: 4 big buffers + energy slab + stats
  float* bufQ = ws;
  float* bufK = bufQ + (long)B * CN;
  float* bufV = bufK + (long)B * CN;
  float* bufO = bufV + (long)B * CN;
  float* bufE = bufO + (long)B * CN;

  long availf = (long)(ws_size / 4) - (long)4 * B * CN - 8L * B * C - 1024;
  int S = 1024;  // query-slab size for N x N attention
  while (S > 128 && (long)B * S * Nsp > availf) S >>= 1;

  float* stats = bufE + (long)B * S * Nsp;
  float* m1 = stats;
  float* r1 = m1 + B * C;
  float* m2 = r1 + B * C;
  float* r2 = m2 + B * C;
  float* m3 = r2 + B * C;
  float* r3 = m3 + B * C;
  float* m4 = r3 + B * C;
  float* r4 = m4 + B * C;

  dim3 blk(256);
  dim3 gConv(Nsp / BNT, C / BMT, B);  // M=C, N=Nsp

  // ======================= Module 1: content self-attn =====================
  row_stats_k<<<B * C, blk, 0, stream>>>(xc, m1, r1, Nsp);
  // q = W0 * mvn(x) + b0 ; k = W1 * mvn(x) + b1 ; v = W2 * x + b2
  gemm_k<false, false, true, true, false><<<gConv, blk, 0, stream>>>(
      cw + 0 * CC, 0, C, xc, CN, Nsp, bufQ, CN, Nsp, cb + 0 * C, nullptr, 0,
      m1, r1, C, C, Nsp, C);
  gemm_k<false, false, true, true, false><<<gConv, blk, 0, stream>>>(
      cw + 1 * CC, 0, C, xc, CN, Nsp, bufK, CN, Nsp, cb + 1 * C, nullptr, 0,
      m1, r1, C, C, Nsp, C);
  gemm_k<false, false, false, true, false><<<gConv, blk, 0, stream>>>(
      cw + 2 * CC, 0, C, xc, CN, Nsp, bufV, CN, Nsp, cb + 2 * C, nullptr, 0,
      nullptr, nullptr, 0, C, Nsp, C);
  for (int i0 = 0; i0 < Nsp; i0 += S) {
    // E[i,j] = sum_c q[c,i0+i] k[c,j]
    gemm_k<true, false, false, false, false>
        <<<dim3(Nsp / BNT, S / BMT, B), blk, 0, stream>>>(
            bufQ + i0, CN, Nsp, bufK, CN, Nsp, bufE, (long)S * Nsp, Nsp,
            nullptr, nullptr, 0, nullptr, nullptr, 0, S, Nsp, C);
    softmax_rows_k<<<B * S, blk, 0, stream>>>(bufE, Nsp);
    // o[c,i0+i] = sum_j v[c,j] attn[i,j]
    gemm_k<false, true, false, false, false>
        <<<dim3(S / BNT, C / BMT, B), blk, 0, stream>>>(
            bufV, CN, Nsp, bufE, (long)S * Nsp, Nsp, bufO + i0, CN, Nsp,
            nullptr, nullptr, 0, nullptr, nullptr, 0, C, S, Nsp);
  }
  // cf = W3 * o + b3 + x  -> d_out
  gemm_k<false, false, false, true, true><<<gConv, blk, 0, stream>>>(
      cw + 3 * CC, 0, C, bufO, CN, Nsp, out, CN, Nsp, cb + 3 * C, xc, CN,
      nullptr, nullptr, 0, C, Nsp, C);

  // ======================= Module 2: style self-attn (channel) =============
  // f = W0*s + b0 ; g = W1*s + b1
  gemm_k<false, false, false, true, false><<<gConv, blk, 0, stream>>>(
      sw + 0 * CC, 0, C, xs, CN, Nsp, bufQ, CN, Nsp, sb + 0 * C, nullptr, 0,
      nullptr, nullptr, 0, C, Nsp, C);
  gemm_k<false, false, false, true, false><<<gConv, blk, 0, stream>>>(
      sw + 1 * CC, 0, C, xs, CN, Nsp, bufK, CN, Nsp, sb + 1 * C, nullptr, 0,
      nullptr, nullptr, 0, C, Nsp, C);
  // E[c,d] = sum_i f[c,i] g[d,i]
  gemm_k<false, true, false, false, false>
      <<<dim3(C / BNT, C / BMT, B), blk, 0, stream>>>(
          bufQ, CN, Nsp, bufK, CN, Nsp, bufE, CC, C, nullptr, nullptr, 0,
          nullptr, nullptr, 0, C, C, Nsp);
  softmax_rows_k<<<B * C, blk, 0, stream>>>(bufE, C);
  row_stats_k<<<B * C, blk, 0, stream>>>(xs, m2, r2, Nsp);
  // h = W2 * mvn(s) + b2
  gemm_k<false, false, true, true, false><<<gConv, blk, 0, stream>>>(
      sw + 2 * CC, 0, C, xs, CN, Nsp, bufV, CN, Nsp, sb + 2 * C, nullptr, 0,
      m2, r2, C, C, Nsp, C);
  // o[c,i] = sum_d attn[d,c] h[d,i]   (A = attn in [K=d, M=c] layout)
  gemm_k<true, false, false, false, false><<<gConv, blk, 0, stream>>>(
      bufE, CC, C, bufV, CN, Nsp, bufO, CN, Nsp, nullptr, nullptr, 0, nullptr,
      nullptr, 0, C, Nsp, C);
  // sf = W3 * o + b3 + s -> bufV
  gemm_k<false, false, false, true, true><<<gConv, blk, 0, stream>>>(
      sw + 3 * CC, 0, C, bufO, CN, Nsp, bufV, CN, Nsp, sb + 3 * C, xs, CN,
      nullptr, nullptr, 0, C, Nsp, C);

  // ======================= Module 3: cross attention =======================
  row_stats_k<<<B * C, blk, 0, stream>>>(out, m3, r3, Nsp);   // cf stats
  row_stats_k<<<B * C, blk, 0, stream>>>(bufV, m4, r4, Nsp);  // sf stats
  // q = W0 * mvn(cf) + b0 ; k = W1 * mvn(sf) + b1 ; v = W2 * sf + b2
  gemm_k<false, false, true, true, false><<<gConv, blk, 0, stream>>>(
      aw + 0 * CC, 0, C, out, CN, Nsp, bufQ, CN, Nsp, abias + 0 * C, nullptr,
      0, m3, r3, C, C, Nsp, C);
  gemm_k<false, false, true, true, false><<<gConv, blk, 0, stream>>>(
      aw + 1 * CC, 0, C, bufV, CN, Nsp, bufK, CN, Nsp, abias + 1 * C, nullptr,
      0, m4, r4, C, C, Nsp, C);
  gemm_k<false, false, false, true, false><<<gConv, blk, 0, stream>>>(
      aw + 2 * CC, 0, C, bufV, CN, Nsp, bufO, CN, Nsp, abias + 2 * C, nullptr,
      0, nullptr, nullptr, 0, C, Nsp, C);
  for (int i0 = 0; i0 < Nsp; i0 += S) {
    gemm_k<true, false, false, false, false>
        <<<dim3(Nsp / BNT, S / BMT, B), blk, 0, stream>>>(
            bufQ + i0, CN, Nsp, bufK, CN, Nsp, bufE, (long)S * Nsp, Nsp,
            nullptr, nullptr, 0, nullptr, nullptr, 0, S, Nsp, C);
    softmax_rows_k<<<B * S, blk, 0, stream>>>(bufE, Nsp);
    gemm_k<false, true, false, false, false>
        <<<dim3(S / BNT, C / BMT, B), blk, 0, stream>>>(
            bufO, CN, Nsp, bufE, (long)S * Nsp, Nsp, bufV + i0, CN, Nsp,
            nullptr, nullptr, 0, nullptr, nullptr, 0, C, S, Nsp);
  }
  // out = W3 * o + b3 + cf  (in-place residual: each thread reads its own
  // d_out element before overwriting it)
  gemm_k<false, false, false, true, true><<<gConv, blk, 0, stream>>>(
      aw + 3 * CC, 0, C, bufV, CN, Nsp, out, CN, Nsp, abias + 3 * C, out, CN,
      nullptr, nullptr, 0, C, Nsp, C);
}

// Round 2
// 1904.834 us; speedup vs baseline: 4.3221x; 4.3221x over previous
//
#include <hip/hip_runtime.h>
#include <math.h>

// Multi_Adaptation_Module on MI355X: all GEMMs via split-bf16 (hi+lo) MFMA,
// 3x mfma_f32_16x16x32_bf16 per product (a_hi*b_hi + a_hi*b_lo + a_lo*b_hi),
// fp32 accumulate. All intermediates stored as hi/lo bf16 planes in NT-
// friendly layouts. B=4, C=512, N=64*64=4096.

#define B_ 4
#define C_ 512
#define N_ 4096
#define TM 128
#define TN 128
#define BK 64

typedef unsigned short u16;
typedef __attribute__((ext_vector_type(8))) short s8v;   // 8 bf16 (4 VGPR)
typedef __attribute__((ext_vector_type(4))) float f4v;

__device__ __forceinline__ u16 f2bf(float x) {
  unsigned u = __float_as_uint(x);
  return (u16)((u + 0x7fffu + ((u >> 16) & 1u)) >> 16);
}
__device__ __forceinline__ float bf2f(u16 h) {
  return __uint_as_float(((unsigned)h) << 16);
}
__device__ __forceinline__ void splitf(float x, u16& h, u16& l) {
  h = f2bf(x);
  l = f2bf(x - bf2f(h));
}

__device__ __forceinline__ void gload16(const void* g, void* l) {
  __builtin_amdgcn_global_load_lds(
      (const __attribute__((address_space(1))) unsigned int*)g,
      (__attribute__((address_space(3))) unsigned int*)l, 16, 0, 0);
}

__device__ __forceinline__ float wave_red_sum(float v) {
#pragma unroll
  for (int off = 32; off > 0; off >>= 1) v += __shfl_xor(v, off, 64);
  return v;
}
__device__ __forceinline__ float wave_red_max(float v) {
#pragma unroll
  for (int off = 32; off > 0; off >>= 1) v = fmaxf(v, __shfl_xor(v, off, 64));
  return v;
}

// ---------------- stats: per (b,c) mean + rstd over N_ (unbiased, eps 1e-5)
__global__ __launch_bounds__(256) void row_stats_k(const float* __restrict__ x,
                                                   float* __restrict__ mean,
                                                   float* __restrict__ rstd) {
  long row = blockIdx.x;
  const float* p = x + row * (long)N_;
  int t = threadIdx.x;
  float s = 0.f, ss = 0.f;
  for (int i = t * 4; i < N_; i += 1024) {
    float4 v = *(const float4*)(p + i);
    s += v.x + v.y + v.z + v.w;
    ss += v.x * v.x + v.y * v.y + v.z * v.z + v.w * v.w;
  }
  __shared__ float rs_[4], rss_[4];
  int wid = t >> 6, lane = t & 63;
  s = wave_red_sum(s);
  ss = wave_red_sum(ss);
  if (lane == 0) { rs_[wid] = s; rss_[wid] = ss; }
  __syncthreads();
  if (t == 0) {
    float S = rs_[0] + rs_[1] + rs_[2] + rs_[3];
    float SS = rss_[0] + rss_[1] + rss_[2] + rss_[3];
    float m = S / (float)N_;
    float var = (SS - (float)N_ * m * m) / (float)(N_ - 1);
    mean[row] = m;
    rstd[row] = rsqrtf(var + 1e-5f);
  }
}

// ---------------- fp32 array -> split planes
__global__ __launch_bounds__(256) void split_arr_k(const float* __restrict__ in,
                                                   u16* __restrict__ h,
                                                   u16* __restrict__ l, long n) {
  long i = ((long)blockIdx.x * 256 + threadIdx.x) * 4;
  if (i >= n) return;
  float4 v = *(const float4*)(in + i);
  u16 ha[4], la[4];
  splitf(v.x, ha[0], la[0]);
  splitf(v.y, ha[1], la[1]);
  splitf(v.z, ha[2], la[2]);
  splitf(v.w, ha[3], la[3]);
  *(ushort4*)(h + i) = make_ushort4(ha[0], ha[1], ha[2], ha[3]);
  *(ushort4*)(l + i) = make_ushort4(la[0], la[1], la[2], la[3]);
}

// ---------------- transpose+MVN+split: X fp32 [C,N] -> o1 = mvn(X)^T split
// [N,C]; optionally o2 = X^T split [N,C]
template <bool HAS2>
__global__ __launch_bounds__(256) void tsplit_k(
    const float* __restrict__ X, const float* __restrict__ mean,
    const float* __restrict__ rstd, u16* __restrict__ o1h,
    u16* __restrict__ o1l, u16* __restrict__ o2h, u16* __restrict__ o2l) {
  __shared__ float tile[64][68];
  const int b = blockIdx.z;
  const int c0 = blockIdx.y * 64, i0 = blockIdx.x * 64;
  const int t = threadIdx.x;
  const int tr = t >> 4, tc = (t & 15) << 2;
  const long CN = (long)C_ * N_;
  const float* Xb = X + (long)b * CN;
#pragma unroll
  for (int p2 = 0; p2 < 4; ++p2) {
    int c = p2 * 16 + tr;
    float4 v = *(const float4*)(Xb + (long)(c0 + c) * N_ + i0 + tc);
    tile[c][tc] = v.x;
    tile[c][tc + 1] = v.y;
    tile[c][tc + 2] = v.z;
    tile[c][tc + 3] = v.w;
  }
  __syncthreads();
  float mv[4], rv[4];
#pragma unroll
  for (int j = 0; j < 4; ++j) {
    mv[j] = mean[b * C_ + c0 + tc + j];
    rv[j] = rstd[b * C_ + c0 + tc + j];
  }
#pragma unroll
  for (int p2 = 0; p2 < 4; ++p2) {
    int ir = p2 * 16 + tr;
    long off = (long)b * CN + (long)(i0 + ir) * C_ + c0 + tc;
    u16 h1[4], l1[4], h2[4], l2[4];
#pragma unroll
    for (int j = 0; j < 4; ++j) {
      float v = tile[tc + j][ir];
      if (HAS2) splitf(v, h2[j], l2[j]);
      float nv = (v - mv[j]) * rv[j];
      splitf(nv, h1[j], l1[j]);
    }
    *(ushort4*)(o1h + off) = make_ushort4(h1[0], h1[1], h1[2], h1[3]);
    *(ushort4*)(o1l + off) = make_ushort4(l1[0], l1[1], l1[2], l1[3]);
    if (HAS2) {
      *(ushort4*)(o2h + off) = make_ushort4(h2[0], h2[1], h2[2], h2[3]);
      *(ushort4*)(o2l + off) = make_ushort4(l2[0], l2[1], l2[2], l2[3]);
    }
  }
}

// ---------------- softmax over rows of 4096, emit split planes
__global__ __launch_bounds__(256) void softmax_split_k(
    const float* __restrict__ E, u16* __restrict__ ph, u16* __restrict__ pl) {
  long row = blockIdx.x;
  const float* p = E + row * (long)N_;
  int t = threadIdx.x;
  float v[16];
  float mx = -3.4e38f;
#pragma unroll
  for (int q = 0; q < 4; ++q) {
    float4 w4 = *(const float4*)(p + t * 16 + q * 4);
    v[q * 4 + 0] = w4.x;
    v[q * 4 + 1] = w4.y;
    v[q * 4 + 2] = w4.z;
    v[q * 4 + 3] = w4.w;
    mx = fmaxf(mx, fmaxf(fmaxf(w4.x, w4.y), fmaxf(w4.z, w4.w)));
  }
  __shared__ float red[4];
  int wid = t >> 6, lane = t & 63;
  mx = wave_red_max(mx);
  if (lane == 0) red[wid] = mx;
  __syncthreads();
  mx = fmaxf(fmaxf(red[0], red[1]), fmaxf(red[2], red[3]));
  float s = 0.f;
#pragma unroll
  for (int i = 0; i < 16; ++i) {
    v[i] = __expf(v[i] - mx);
    s += v[i];
  }
  __syncthreads();
  s = wave_red_sum(s);
  if (lane == 0) red[wid] = s;
  __syncthreads();
  s = red[0] + red[1] + red[2] + red[3];
  float inv = 1.f / s;
  long ob = row * (long)N_ + t * 16;
#pragma unroll
  for (int q = 0; q < 4; ++q) {
    u16 ha[4], la[4];
#pragma unroll
    for (int j = 0; j < 4; ++j) splitf(v[q * 4 + j] * inv, ha[j], la[j]);
    *(ushort4*)(ph + ob + q * 4) = make_ushort4(ha[0], ha[1], ha[2], ha[3]);
    *(ushort4*)(pl + ob + q * 4) = make_ushort4(la[0], la[1], la[2], la[3]);
  }
}

// ---------------- style softmax: rows of 512, write TRANSPOSED split planes
__global__ __launch_bounds__(256) void softmax_t_k(const float* __restrict__ E2,
                                                   u16* __restrict__ ph,
                                                   u16* __restrict__ pl) {
  int b = blockIdx.x >> 9;
  int x = blockIdx.x & 511;
  const float* p = E2 + ((long)b * C_ + x) * C_;
  int t = threadIdx.x;
  float v0 = p[t * 2], v1 = p[t * 2 + 1];
  float mx = fmaxf(v0, v1);
  __shared__ float red[4];
  int wid = t >> 6, lane = t & 63;
  mx = wave_red_max(mx);
  if (lane == 0) red[wid] = mx;
  __syncthreads();
  mx = fmaxf(fmaxf(red[0], red[1]), fmaxf(red[2], red[3]));
  v0 = __expf(v0 - mx);
  v1 = __expf(v1 - mx);
  float s = v0 + v1;
  __syncthreads();
  s = wave_red_sum(s);
  if (lane == 0) red[wid] = s;
  __syncthreads();
  s = red[0] + red[1] + red[2] + red[3];
  float inv = 1.f / s;
  long base = (long)b * C_ * C_;
  u16 h, l;
  splitf(v0 * inv, h, l);
  ph[base + (long)(t * 2) * C_ + x] = h;
  pl[base + (long)(t * 2) * C_ + x] = l;
  splitf(v1 * inv, h, l);
  ph[base + (long)(t * 2 + 1) * C_ + x] = h;
  pl[base + (long)(t * 2 + 1) * C_ + x] = l;
}

// ---------------- split-K reduction: sum nsplit fp32 partials -> split or f32
template <bool SPLITOUT>
__global__ __launch_bounds__(256) void redk_k(
    const float* __restrict__ P, long pKS, long perB, int nsplit,
    float* __restrict__ of, u16* __restrict__ oh, u16* __restrict__ ol,
    long oBS, long oOff, long total) {
  long e = ((long)blockIdx.x * 256 + threadIdx.x) * 4;
  if (e >= total) return;
  long b = e / perB, rem = e - b * perB;
  const float* p0 = P + b * perB + rem;
  float4 s = *(const float4*)p0;
  for (int k = 1; k < nsplit; ++k) {
    float4 t = *(const float4*)(p0 + (long)k * pKS);
    s.x += t.x;
    s.y += t.y;
    s.z += t.z;
    s.w += t.w;
  }
  if (SPLITOUT) {
    u16 ha[4], la[4];
    splitf(s.x, ha[0], la[0]);
    splitf(s.y, ha[1], la[1]);
    splitf(s.z, ha[2], la[2]);
    splitf(s.w, ha[3], la[3]);
    *(ushort4*)(oh + b * oBS + oOff + rem) =
        make_ushort4(ha[0], ha[1], ha[2], ha[3]);
    *(ushort4*)(ol + b * oBS + oOff + rem) =
        make_ushort4(la[0], la[1], la[2], la[3]);
  } else {
    *(float4*)(of + b * perB + rem) = s;
  }
}

// ---------------- the split-bf16 MFMA NT GEMM ------------------------------
// C[b][m][n] = sum_k A[m,k]*B[n,k]; A,B given as hi/lo bf16 planes, K-contig.
// OUTM: 0 = fp32 (+res), 1 = split planes. BIAS: 0 none, 1 per-m, 2 per-n.
template <int OUTM, int BIAS, bool RES>
__global__ __launch_bounds__(256, 2) void mm_k(
    const u16* __restrict__ Ah, const u16* __restrict__ Al, long aBS, int lda,
    const u16* __restrict__ Bh, const u16* __restrict__ Bl, long bBS, int ldb,
    float* Of, u16* __restrict__ Oh, u16* __restrict__ Ol, long oBS, long oKS,
    int ldo, const float* __restrict__ bias, const float* resp, long rBS,
    int K, int nsplit) {
  __shared__ u16 lds[4][128 * 64];
  const int b = blockIdx.z / nsplit;
  const int ks = blockIdx.z % nsplit;
  const int Kc = K / nsplit;
  const int k0beg = ks * Kc;
  const int m0 = blockIdx.y * TM, n0 = blockIdx.x * TN;
  const int t = threadIdx.x, lane = t & 63, wid = t >> 6;
  const int wm = (wid >> 1) * 64, wn = (wid & 1) * 64;

  const u16* myplane;
  int myld;
  long myrow0;
  if (wid == 0) { myplane = Ah + (long)b * aBS; myld = lda; myrow0 = m0; }
  else if (wid == 1) { myplane = Al + (long)b * aBS; myld = lda; myrow0 = m0; }
  else if (wid == 2) { myplane = Bh + (long)b * bBS; myld = ldb; myrow0 = n0; }
  else { myplane = Bl + (long)b * bBS; myld = ldb; myrow0 = n0; }
  u16* mylds = &lds[wid][0];
  const int sr = lane >> 3;      // row within 8-row staging group
  const int kslot = lane & 7;    // 16B slot within 128B row

  f4v acc[4][4];
#pragma unroll
  for (int i = 0; i < 4; ++i)
#pragma unroll
    for (int j = 0; j < 4; ++j) acc[i][j] = (f4v){0.f, 0.f, 0.f, 0.f};

  const int lr = lane & 15;
  const int ksl = lane >> 4;
  const u16* l0 = &lds[0][0];
  const u16* l1 = &lds[1][0];
  const u16* l2 = &lds[2][0];
  const u16* l3 = &lds[3][0];

  for (int k0 = k0beg; k0 < k0beg + Kc; k0 += BK) {
#pragma unroll
    for (int s = 0; s < 16; ++s) {
      int r = s * 8 + sr;
      int kb = (kslot * 16) ^ ((r & 7) << 4);  // byte offset in 128B row
      const u16* gp = myplane + (myrow0 + r) * (long)myld + k0;
      gload16((const char*)gp + kb, mylds + s * 512);
    }
    __syncthreads();
#pragma unroll
    for (int kk = 0; kk < 2; ++kk) {
      s8v ah[4], al[4], bh[4], bl[4];
#pragma unroll
      for (int f = 0; f < 4; ++f) {
        int ra = wm + f * 16 + lr;
        int ka = (kk * 64 + ksl * 16) ^ ((ra & 7) << 4);
        ah[f] = *(const s8v*)(l0 + ra * 64 + (ka >> 1));
        al[f] = *(const s8v*)(l1 + ra * 64 + (ka >> 1));
        int rb = wn + f * 16 + lr;
        int kb2 = (kk * 64 + ksl * 16) ^ ((rb & 7) << 4);
        bh[f] = *(const s8v*)(l2 + rb * 64 + (kb2 >> 1));
        bl[f] = *(const s8v*)(l3 + rb * 64 + (kb2 >> 1));
      }
#pragma unroll
      for (int i = 0; i < 4; ++i)
#pragma unroll
        for (int j = 0; j < 4; ++j) {
          acc[i][j] = __builtin_amdgcn_mfma_f32_16x16x32_bf16(ah[i], bh[j],
                                                              acc[i][j], 0, 0, 0);
          acc[i][j] = __builtin_amdgcn_mfma_f32_16x16x32_bf16(ah[i], bl[j],
                                                              acc[i][j], 0, 0, 0);
          acc[i][j] = __builtin_amdgcn_mfma_f32_16x16x32_bf16(al[i], bh[j],
                                                              acc[i][j], 0, 0, 0);
        }
    }
    __syncthreads();
  }

  const float* resb = RES ? (resp + (long)b * rBS) : nullptr;
  long obase = (long)b * oBS + (long)ks * oKS;
#pragma unroll
  for (int i = 0; i < 4; ++i) {
#pragma unroll
    for (int j = 0; j < 4; ++j) {
#pragma unroll
      for (int e = 0; e < 4; ++e) {
        int m = m0 + wm + i * 16 + ksl * 4 + e;
        int n = n0 + wn + j * 16 + lr;
        float v = acc[i][j][e];
        if (BIAS == 1) v += bias[m];
        if (BIAS == 2) v += bias[n];
        long o = obase + (long)m * ldo + n;
        if (OUTM == 0) {
          if (RES) v += resb[(long)m * ldo + n];
          Of[o] = v;
        } else {
          u16 h, l;
          splitf(v, h, l);
          Oh[o] = h;
          Ol[o] = l;
        }
      }
    }
  }
}

// ===========================================================================
extern "C" void kernel_launch(void* const* d_in, const int* in_sizes, int n_in,
                              void* d_out, int out_size, void* d_ws,
                              size_t ws_size, hipStream_t stream) {
  (void)in_sizes; (void)n_in; (void)out_size;
  const long CN = (long)C_ * N_;
  const long CC = (long)C_ * C_;

  const float* xc = (const float*)d_in[0];
  const float* xs = (const float*)d_in[1];
  const float* cw = (const float*)d_in[2];
  const float* cb = (const float*)d_in[3];
  const float* sw = (const float*)d_in[4];
  const float* sb = (const float*)d_in[5];
  const float* aw = (const float*)d_in[6];
  const float* ab = (const float*)d_in[7];
  float* out = (float*)d_out;

  char* w = (char*)d_ws;
  auto carve = [&](size_t bytes) {
    char* r = w;
    w += (bytes + 255) & ~(size_t)255;
    return r;
  };
  u16* cwh = (u16*)carve(4 * CC * 2);
  u16* cwl = (u16*)carve(4 * CC * 2);
  u16* swh = (u16*)carve(4 * CC * 2);
  u16* swl = (u16*)carve(4 * CC * 2);
  u16* awh = (u16*)carve(4 * CC * 2);
  u16* awl = (u16*)carve(4 * CC * 2);
  float* stats = (float*)carve(8 * B_ * C_ * 4);
  float* m1 = stats, *r1 = m1 + B_ * C_, *m2 = r1 + B_ * C_, *r2 = m2 + B_ * C_;
  float* m3 = r2 + B_ * C_, *r3 = m3 + B_ * C_, *m4 = r3 + B_ * C_,
       *r4 = m4 + B_ * C_;
  float* E2buf = (float*)carve(B_ * CC * 4);
  u16* aTh = (u16*)carve(B_ * CC * 2);
  u16* aTl = (u16*)carve(B_ * CC * 2);
  const size_t SLOT = (size_t)B_ * CN * 4;  // 2 planes of u16 OR one fp32 buf
  char* s0 = carve(SLOT);
  char* s1 = carve(SLOT);
  char* s2 = carve(SLOT);
  char* s3 = carve(SLOT);
  size_t used = (size_t)(w - (char*)d_ws);
  int S = 1024;
  while (S > 128 && used + 2 * ((size_t)B_ * S * N_ * 4) > ws_size) S >>= 1;
  float* Ereg = (float*)carve((size_t)B_ * S * N_ * 4);
  u16* atH = (u16*)carve((size_t)B_ * S * N_ * 2);
  u16* atL = (u16*)carve((size_t)B_ * S * N_ * 2);

  struct SP { u16* h; u16* l; };
  auto slot = [&](char* p) { SP r; r.h = (u16*)p; r.l = (u16*)p + B_ * CN; return r; };
  SP sA = slot(s0), sB = slot(s1), sC = slot(s2), sD = slot(s3);

  const int nsPV = 8;
  int e2s = (int)((size_t)B_ * S * N_ * 4 / ((size_t)B_ * CC * 4));
  if (e2s > 8) e2s = 8;
  if (e2s < 1) e2s = 1;

  dim3 blk(256);
  dim3 gQ(4, 32, B_);    // M=4096, N=512
  dim3 gV(32, 4, B_);    // M=512,  N=4096
  dim3 gTs(N_ / 64, C_ / 64, B_);

  // weights -> split planes
  split_arr_k<<<1024, blk, 0, stream>>>(cw, cwh, cwl, 4 * CC);
  split_arr_k<<<1024, blk, 0, stream>>>(sw, swh, swl, 4 * CC);
  split_arr_k<<<1024, blk, 0, stream>>>(aw, awh, awl, 4 * CC);

  // ===================== Module 1: content self-attn =======================
  row_stats_k<<<B_ * C_, blk, 0, stream>>>(xc, m1, r1);
  tsplit_k<true><<<gTs, blk, 0, stream>>>(xc, m1, r1, sA.h, sA.l, sB.h, sB.l);
  // Q1[i,c] (slotC), K1[i,c] (slotD): A=xnT, B=W
  mm_k<1, 2, false><<<gQ, blk, 0, stream>>>(sA.h, sA.l, CN, C_, cwh, cwl, 0,
      C_, nullptr, sC.h, sC.l, CN, 0, C_, cb, nullptr, 0, C_, 1);
  mm_k<1, 2, false><<<gQ, blk, 0, stream>>>(sA.h, sA.l, CN, C_, cwh + CC,
      cwl + CC, 0, C_, nullptr, sD.h, sD.l, CN, 0, C_, cb + C_, nullptr, 0, C_, 1);
  // V1[c,i] (slotA): A=W2, B=xT
  mm_k<1, 1, false><<<gV, blk, 0, stream>>>(cwh + 2 * CC, cwl + 2 * CC, 0, C_,
      sB.h, sB.l, CN, C_, nullptr, sA.h, sA.l, CN, 0, N_, cb + 2 * C_, nullptr,
      0, C_, 1);
  for (int i0 = 0; i0 < N_; i0 += S) {
    mm_k<0, 0, false><<<dim3(32, S / 128, B_), blk, 0, stream>>>(
        sC.h + (long)i0 * C_, sC.l + (long)i0 * C_, CN, C_, sD.h, sD.l, CN, C_,
        Ereg, nullptr, nullptr, (long)S * N_, 0, N_, nullptr, nullptr, 0, C_, 1);
    softmax_split_k<<<B_ * S, blk, 0, stream>>>(Ereg, atH, atL);
    mm_k<0, 0, false><<<dim3(4, S / 128, B_ * nsPV), blk, 0, stream>>>(
        atH, atL, (long)S * N_, N_, sA.h, sA.l, CN, N_, Ereg, nullptr, nullptr,
        (long)S * C_, (long)B_ * S * C_, C_, nullptr, nullptr, 0, N_, nsPV);
    redk_k<true><<<(B_ * S * C_) / 1024, blk, 0, stream>>>(
        Ereg, (long)B_ * S * C_, (long)S * C_, nsPV, nullptr, sB.h, sB.l, CN,
        (long)i0 * C_, (long)B_ * S * C_);
  }
  // cf = W3 @ o1 + b3 + x -> d_out (fp32 [C,N])
  mm_k<0, 1, true><<<gV, blk, 0, stream>>>(cwh + 3 * CC, cwl + 3 * CC, 0, C_,
      sB.h, sB.l, CN, C_, out, nullptr, nullptr, CN, 0, N_, cb + 3 * C_, xc,
      CN, C_, 1);

  // ===================== Module 2: style self-attn (channel) ===============
  row_stats_k<<<B_ * C_, blk, 0, stream>>>(xs, m2, r2);
  tsplit_k<true><<<gTs, blk, 0, stream>>>(xs, m2, r2, sA.h, sA.l, sC.h, sC.l);
  // f (slotB), g (slotD): [C,N], A=W, B=sT
  mm_k<1, 1, false><<<gV, blk, 0, stream>>>(swh, swl, 0, C_, sC.h, sC.l, CN,
      C_, nullptr, sB.h, sB.l, CN, 0, N_, sb, nullptr, 0, C_, 1);
  mm_k<1, 1, false><<<gV, blk, 0, stream>>>(swh + CC, swl + CC, 0, C_, sC.h,
      sC.l, CN, C_, nullptr, sD.h, sD.l, CN, 0, N_, sb + C_, nullptr, 0, C_, 1);
  // hT[i,d] (slotC): A=snT, B=W2
  mm_k<1, 2, false><<<gQ, blk, 0, stream>>>(sA.h, sA.l, CN, C_, swh + 2 * CC,
      swl + 2 * CC, 0, C_, nullptr, sC.h, sC.l, CN, 0, C_, sb + 2 * C_,
      nullptr, 0, C_, 1);
  // E2 = f g^T (split-K partials in Ereg) -> E2buf
  mm_k<0, 0, false><<<dim3(4, 4, B_ * e2s), blk, 0, stream>>>(
      sB.h, sB.l, CN, N_, sD.h, sD.l, CN, N_, Ereg, nullptr, nullptr, CC,
      (long)B_ * CC, C_, nullptr, nullptr, 0, N_, e2s);
  redk_k<false><<<(B_ * (int)CC) / 1024, blk, 0, stream>>>(
      Ereg, (long)B_ * CC, CC, e2s, E2buf, nullptr, nullptr, 0, 0,
      (long)B_ * CC);
  softmax_t_k<<<B_ * C_, blk, 0, stream>>>(E2buf, aTh, aTl);
  // o2T[i,c] (slotA): A=hT, B=attnT
  mm_k<1, 0, false><<<gQ, blk, 0, stream>>>(sC.h, sC.l, CN, C_, aTh, aTl, CC,
      C_, nullptr, sA.h, sA.l, CN, 0, C_, nullptr, nullptr, 0, C_, 1);
  // sf = W3 @ o2 + b3 + s -> slotB as fp32 [C,N]
  float* sfF = (float*)s1;
  mm_k<0, 1, true><<<gV, blk, 0, stream>>>(swh + 3 * CC, swl + 3 * CC, 0, C_,
      sA.h, sA.l, CN, C_, sfF, nullptr, nullptr, CN, 0, N_, sb + 3 * C_, xs,
      CN, C_, 1);

  // ===================== Module 3: cross attention =========================
  row_stats_k<<<B_ * C_, blk, 0, stream>>>(out, m3, r3);
  row_stats_k<<<B_ * C_, blk, 0, stream>>>(sfF, m4, r4);
  tsplit_k<false><<<gTs, blk, 0, stream>>>(out, m3, r3, sC.h, sC.l, nullptr,
                                           nullptr);                 // cfnT
  tsplit_k<true><<<gTs, blk, 0, stream>>>(sfF, m4, r4, sD.h, sD.l, sA.h, sA.l);
  // Q3 (slotB): A=cfnT, B=W0a ; K3 (slotC): A=sfnT, B=W1a
  mm_k<1, 2, false><<<gQ, blk, 0, stream>>>(sC.h, sC.l, CN, C_, awh, awl, 0,
      C_, nullptr, sB.h, sB.l, CN, 0, C_, ab, nullptr, 0, C_, 1);
  mm_k<1, 2, false><<<gQ, blk, 0, stream>>>(sD.h, sD.l, CN, C_, awh + CC,
      awl + CC, 0, C_, nullptr, sC.h, sC.l, CN, 0, C_, ab + C_, nullptr, 0,
      C_, 1);
  // V3 (slotD): A=W2a, B=sfT
  mm_k<1, 1, false><<<gV, blk, 0, stream>>>(awh + 2 * CC, awl + 2 * CC, 0, C_,
      sA.h, sA.l, CN, C_, nullptr, sD.h, sD.l, CN, 0, N_, ab + 2 * C_, nullptr,
      0, C_, 1);
  for (int i0 = 0; i0 < N_; i0 += S) {
    mm_k<0, 0, false><<<dim3(32, S / 128, B_), blk, 0, stream>>>(
        sB.h + (long)i0 * C_, sB.l + (long)i0 * C_, CN, C_, sC.h, sC.l, CN, C_,
        Ereg, nullptr, nullptr, (long)S * N_, 0, N_, nullptr, nullptr, 0, C_, 1);
    softmax_split_k<<<B_ * S, blk, 0, stream>>>(Ereg, atH, atL);
    mm_k<0, 0, false><<<dim3(4, S / 128, B_ * nsPV), blk, 0, stream>>>(
        atH, atL, (long)S * N_, N_, sD.h, sD.l, CN, N_, Ereg, nullptr, nullptr,
        (long)S * C_, (long)B_ * S * C_, C_, nullptr, nullptr, 0, N_, nsPV);
    redk_k<true><<<(B_ * S * C_) / 1024, blk, 0, stream>>>(
        Ereg, (long)B_ * S * C_, (long)S * C_, nsPV, nullptr, sA.h, sA.l, CN,
        (long)i0 * C_, (long)B_ * S * C_);
  }
  // out = W3a @ o3 + b3 + cf (in-place residual on d_out)
  mm_k<0, 1, true><<<gV, blk, 0, stream>>>(awh + 3 * CC, awl + 3 * CC, 0, C_,
      sA.h, sA.l, CN, C_, out, nullptr, nullptr, CN, 0, N_, ab + 3 * C_, out,
      CN, C_, 1);
}